// Round 14
// baseline (597.378 us; speedup 1.0000x reference)
//
#include <hip/hip_runtime.h>

typedef unsigned short u16;
typedef unsigned int u32;
typedef __bf16 bf16x8 __attribute__((ext_vector_type(8)));
typedef float f32x4 __attribute__((ext_vector_type(4)));

#define N 4096
#define KD 128
#define NSTRIP 32
#define W 128            // strip width (u16); 256B per row
#define ROWB 256
#define CH 32            // rows per block
#define STB 16           // steps per block (2 rows/step)
#define NBLK 132         // ceil((2048+63+1)/16)
#define HUGEV 3.0e38f
#define TS 128
#define PADK 136

__device__ __forceinline__ u16 f2bf(float v) {
  u32 u = __float_as_uint(v);
  u += 0x7fffu + ((u >> 16) & 1u);   // RNE
  return (u16)(u >> 16);
}
__device__ __forceinline__ float bf2f(u16 b) { return __uint_as_float(((u32)b) << 16); }
__device__ __forceinline__ float bfround(float v) { return bf2f(f2bf(v)); }

__device__ __forceinline__ float dpp_shr1(float oldv, float src) {
  return __int_as_float(__builtin_amdgcn_update_dpp(
      __float_as_int(oldv), __float_as_int(src), 0x138, 0xF, 0xF, false));
}

__device__ __forceinline__ void gload_lds16(const void* g, void* l) {
  __builtin_amdgcn_global_load_lds((const __attribute__((address_space(1))) u32*)g,
                                   (__attribute__((address_space(3))) u32*)l, 16, 0, 0);
}

// ---------------- norms (of bf16-rounded points) + edge sentinel init ----------------
__global__ __launch_bounds__(256) void norms_kernel(const float* __restrict__ pred,
                                                    const float* __restrict__ tgt,
                                                    float* __restrict__ na, float* __restrict__ nb,
                                                    float* __restrict__ edgeG) {
  const int t = blockIdx.x * 256 + threadIdx.x;
  if (t < NSTRIP * N) edgeG[t] = -1.0f;          // sentinel: DP values always >= 0
  int gw = blockIdx.x * 4 + (threadIdx.x >> 6);
  int lane = threadIdx.x & 63;
  const float* base = (gw < N) ? (pred + (size_t)gw * KD) : (tgt + (size_t)(gw - N) * KD);
  float2 v = ((const float2*)base)[lane];
  float x = bfround(v.x), y = bfround(v.y);
  float s = x * x + y * y;
  #pragma unroll
  for (int off = 32; off > 0; off >>= 1) s += __shfl_xor(s, off);
  if (lane == 0) { if (gw < N) na[gw] = s; else nb[gw - N] = s; }
}

// ---------------- C2 = |a|^2 + |b|^2 - 2 a.b  (bf16, row-major) ----------------
__global__ __launch_bounds__(256) void gemm_kernel(const float* __restrict__ A, const float* __restrict__ B,
                                                   const float* __restrict__ na, const float* __restrict__ nb,
                                                   u16* __restrict__ C2) {
  __shared__ u16 As[TS * PADK];
  __shared__ u16 Bs[TS * PADK];
  const int bi = blockIdx.y, bj = blockIdx.x;
  const int tid = threadIdx.x;
  {
    int row = tid >> 1, half = (tid & 1) * 64;
    const float* ga = A + (size_t)(bi * TS + row) * KD + half;
    const float* gb = B + (size_t)(bj * TS + row) * KD + half;
    u16* la = As + row * PADK + half;
    u16* lb = Bs + row * PADK + half;
    #pragma unroll
    for (int v = 0; v < 16; ++v) {
      float4 fa = ((const float4*)ga)[v];
      float4 fb = ((const float4*)gb)[v];
      *(ushort4*)(la + v * 4) = make_ushort4(f2bf(fa.x), f2bf(fa.y), f2bf(fa.z), f2bf(fa.w));
      *(ushort4*)(lb + v * 4) = make_ushort4(f2bf(fb.x), f2bf(fb.y), f2bf(fb.z), f2bf(fb.w));
    }
  }
  __syncthreads();
  const int wid = tid >> 6, lane = tid & 63;
  const int wr = (wid >> 1) * 64, wc = (wid & 1) * 64;
  const int l15 = lane & 15, l4 = lane >> 4;
  f32x4 acc[4][4] = {};
  #pragma unroll
  for (int ks = 0; ks < 4; ++ks) {
    bf16x8 af[4], bq[4];
    const int ko = ks * 32 + l4 * 8;
    #pragma unroll
    for (int m = 0; m < 4; ++m) af[m] = *(const bf16x8*)(As + (wr + m * 16 + l15) * PADK + ko);
    #pragma unroll
    for (int n = 0; n < 4; ++n) bq[n] = *(const bf16x8*)(Bs + (wc + n * 16 + l15) * PADK + ko);
    #pragma unroll
    for (int m = 0; m < 4; ++m)
      #pragma unroll
      for (int n = 0; n < 4; ++n)
        acc[m][n] = __builtin_amdgcn_mfma_f32_16x16x32_bf16(af[m], bq[n], acc[m][n], 0, 0, 0);
  }
  #pragma unroll
  for (int m = 0; m < 4; ++m) {
    const int r0 = bi * TS + wr + m * 16 + l4 * 4;
    #pragma unroll
    for (int n = 0; n < 4; ++n) {
      const int col = bj * TS + wc + n * 16 + l15;
      const float nbv = nb[col];
      #pragma unroll
      for (int e = 0; e < 4; ++e) {
        const int r = r0 + e;
        float d2v = fmaxf(na[r] + nbv - 2.0f * acc[m][n][e], 0.0f);
        C2[(size_t)r * N + col] = f2bf(d2v);
      }
    }
  }
}

// ---------------- wavefront DP: 2 rows x 2 cols per lane per step ----------------
// chain/step: 2 dpp (parallel) -> o00 -> {o01,o10} -> o11  == 7 deps / 2 rows.
#define STEPR2(CU0, CU1, EAv, EBv) { \
  const float La = dpp_shr1((EAv), E0); \
  const float Lb = dpp_shr1((EBv), D1); \
  const float c00 = __uint_as_float((CU0) << 16); \
  const float c01 = __uint_as_float((CU0) & 0xFFFF0000u); \
  const float c10 = __uint_as_float((CU1) << 16); \
  const float c11 = __uint_as_float((CU1) & 0xFFFF0000u); \
  const float o00 = fmaxf(c00, fminf(fminf(D0, Lbp), La)); \
  const float o01 = fmaxf(c01, fminf(fminf(D1, D0), o00)); \
  const float o10 = fmaxf(c10, fminf(fminf(o00, La), Lb)); \
  const float o11 = fmaxf(c11, fminf(fminf(o01, o00), o10)); \
  D0 = o10; D1 = o11; E0 = o01; Lbp = Lb; \
}

#define EOUTW { \
  if (e63) { eout[eix] = E0; eout[eix + 1] = D1; } \
  eix = (eix + 2) & 63; \
}

#define LDGR(EA4, EB4, CV, GG) { \
  EA4 = *(const float4*)(elds + 8 * (GG)); \
  EB4 = *(const float4*)(elds + 8 * (GG) + 4); \
  { const u32 a0 = cbs, a1 = (cbs + 512) & 0xFFFFu, a2 = (cbs + 1024) & 0xFFFFu, a3 = (cbs + 1536) & 0xFFFFu; \
    CV##u0 = *(const u32*)(clb + a0); CV##v0 = *(const u32*)(clb + a0 + 256); \
    CV##u1 = *(const u32*)(clb + a1); CV##v1 = *(const u32*)(clb + a1 + 256); \
    CV##u2 = *(const u32*)(clb + a2); CV##v2 = *(const u32*)(clb + a2 + 256); \
    CV##u3 = *(const u32*)(clb + a3); CV##v3 = *(const u32*)(clb + a3 + 256); } \
  cbs = (cbs + 2048) & 0xFFFFu; \
}

#define CGR(EA4, EB4, CV) { \
  STEPR2(CV##u0, CV##v0, EA4.x, EA4.y) EOUTW \
  STEPR2(CV##u1, CV##v1, EA4.z, EA4.w) EOUTW \
  STEPR2(CV##u2, CV##v2, EB4.x, EB4.y) EOUTW \
  STEPR2(CV##u3, CV##v3, EB4.z, EB4.w) EOUTW \
}

__global__ __launch_bounds__(64) void dp_kernel(const u16* __restrict__ C2, float* __restrict__ edgeG,
                                                float* __restrict__ out) {
  __shared__ u16 win[256 * W];                        // 64 KB: 8-slot ring (256 rows)
  __shared__ __align__(16) float elds[32];
  __shared__ __align__(16) float eout[64];
  const int bid = blockIdx.x;
  const int S = ((bid & 7) << 2) | (bid >> 3);        // 4 consecutive strips per XCD
  const int lane = threadIdx.x;
  const u16* cbase = C2 + (size_t)S * W;
  const char* clb = (const char*)win;
  const bool s0 = (S == 0);
  const bool do_edge = (S != NSTRIP - 1);
  const bool e63 = do_edge && (lane == 63);
  const bool l32 = lane < 32;
  float* eB = edgeG + (size_t)S * N;
  float* eI = edgeG + (size_t)(S - 1) * N;            // producer edges (S>0 only)

  if (s0 && l32) elds[lane] = HUGEV;                  // strip 0: left-of-col-0 = +inf

  float D0 = HUGEV, D1 = HUGEV, E0 = HUGEV;
  float Lbp = (s0 && lane == 0) ? -HUGEV : HUGEV;     // corner: D[0][0]=c[0][0]

  auto STAGE = [&](int c) {
    const int lrow = lane >> 4, lcol = (lane & 15) * 8;
    const u16* g0 = cbase + (size_t)(c * CH + lrow) * N + lcol;
    u16* l0 = win + ((c & 7) * CH) * W;
    #pragma unroll
    for (int n = 0; n < 8; ++n) gload_lds16(g0 + (size_t)(4 * n) * N, l0 + n * 512);
  };

  float v0p = HUGEV;
  if (S > 0 && l32)
    v0p = __hip_atomic_fetch_add(eI + lane, 0.0f, __ATOMIC_RELAXED, __HIP_MEMORY_SCOPE_AGENT);
  STAGE(0);

  for (int q = 0; q < NBLK; ++q) {
    // (A) drain STAGE(q) + old RMWs/stores (all >= 1 block old)
    asm volatile("s_waitcnt vmcnt(0)" ::: "memory");
    __builtin_amdgcn_sched_barrier(0);

    // (B) validate prefetched edges (rows 32q..32q+31), commit to elds
    if (S > 0 && q <= 127) {
      int it = 0;
      while (__any(v0p < 0.0f)) {
        __builtin_amdgcn_s_sleep(1);
        if (l32)
          v0p = __hip_atomic_fetch_add(eI + q * 32 + lane, 0.0f,
                                       __ATOMIC_RELAXED, __HIP_MEMORY_SCOPE_AGENT);
        if (++it > (1 << 20)) break;
      }
      if (l32) elds[lane] = v0p;
    }

    // (C) prefetch next block's edges + stage next chunk
    if (S > 0 && q + 1 <= 127 && l32)
      v0p = __hip_atomic_fetch_add(eI + (q + 1) * 32 + lane, 0.0f,
                                   __ATOMIC_RELAXED, __HIP_MEMORY_SCOPE_AGENT);
    else
      v0p = HUGEV;
    if (q + 1 < 128) STAGE(q + 1);

    asm volatile("s_waitcnt lgkmcnt(0)" ::: "memory");
    __builtin_amdgcn_sched_barrier(0);

    // (D) compute 16 steps (rows 2 per step); ring row = (32q - 2*lane) & 255
    u32 cbs = (((u32)(32 * q - 2 * lane)) & 255u) * ROWB + lane * 4;
    int eix = (32 * q - 126) & 63;

    if (q >= 4 && q <= 127) {
      float4 Aea, Aeb, Bea, Beb;
      u32 Au0, Av0, Au1, Av1, Au2, Av2, Au3, Av3;
      u32 Bu0, Bv0, Bu1, Bv1, Bu2, Bv2, Bu3, Bv3;
      LDGR(Aea, Aeb, A, 0)
      LDGR(Bea, Beb, B, 1)
      CGR(Aea, Aeb, A)
      LDGR(Aea, Aeb, A, 2)
      CGR(Bea, Beb, B)
      LDGR(Bea, Beb, B, 3)
      CGR(Aea, Aeb, A)
      CGR(Bea, Beb, B)
    } else {
      for (int k = 0; k < STB; ++k) {
        const int s = STB * q + k;
        const int i0 = 2 * (s - lane);
        const bool act = (u32)i0 <= 4094u;
        const u32 cu0 = *(const u32*)(clb + cbs);
        const u32 cu1 = *(const u32*)(clb + cbs + 256);
        cbs = (cbs + 512) & 0xFFFFu;
        const float ea = elds[(2 * k) & 31];
        const float eb = elds[(2 * k + 1) & 31];
        const float La = dpp_shr1(ea, E0);
        const float Lb = dpp_shr1(eb, D1);
        const float c00 = __uint_as_float(cu0 << 16);
        const float c01 = __uint_as_float(cu0 & 0xFFFF0000u);
        const float c10 = __uint_as_float(cu1 << 16);
        const float c11 = __uint_as_float(cu1 & 0xFFFF0000u);
        const float o00 = fmaxf(c00, fminf(fminf(D0, Lbp), La));
        const float o01 = fmaxf(c01, fminf(fminf(D1, D0), o00));
        const float o10 = fmaxf(c10, fminf(fminf(o00, La), Lb));
        const float o11 = fmaxf(c11, fminf(fminf(o01, o00), o10));
        if (act) { D0 = o10; D1 = o11; E0 = o01; Lbp = Lb; }
        if (e63 && act) { eout[i0 & 63] = o01; eout[(i0 + 1) & 63] = o11; }
      }
    }

    // (E) publish rows [32q-126, 32q-95]: plain stores, data IS the flag
    if (do_edge) {
      asm volatile("s_waitcnt lgkmcnt(0)" ::: "memory");
      __builtin_amdgcn_sched_barrier(0);
      const int r = 32 * q - 126 + lane;
      if (l32 && r >= 0 && r < N) {
        const float v = eout[r & 63];
        __hip_atomic_store(eB + r, v, __ATOMIC_RELAXED, __HIP_MEMORY_SCOPE_AGENT);
      }
    }
  }

  if (S == NSTRIP - 1 && lane == 63) out[0] = sqrtf(fmaxf(D1, 0.0f));
}

extern "C" void kernel_launch(void* const* d_in, const int* in_sizes, int n_in,
                              void* d_out, int out_size, void* d_ws, size_t ws_size,
                              hipStream_t stream) {
  const float* pred = (const float*)d_in[0];
  const float* tgt  = (const float*)d_in[1];
  char* ws = (char*)d_ws;
  u16* C2   = (u16*)ws;                                   // 32 MB row-major d2 (bf16)
  float* na = (float*)(ws + (size_t)N * N * 2);
  float* nb = na + N;
  float* edgeG = nb + N;                                  // 32*N floats, sentinel-init'd
  float* out = (float*)d_out;

  hipLaunchKernelGGL(norms_kernel, dim3(2048), dim3(256), 0, stream, pred, tgt, na, nb, edgeG);
  hipLaunchKernelGGL(gemm_kernel, dim3(32, 32), dim3(256), 0, stream, pred, tgt, na, nb, C2);
  hipLaunchKernelGGL(dp_kernel, dim3(NSTRIP), dim3(64), 0, stream, C2, edgeG, out);
}